// Round 11
// baseline (226.566 us; speedup 1.0000x reference)
//
#include <hip/hip_runtime.h>

typedef __bf16 bf16;
typedef __bf16 bf16x8 __attribute__((ext_vector_type(8)));
typedef __bf16 bf16x4 __attribute__((ext_vector_type(4)));
typedef __bf16 bf16x2 __attribute__((ext_vector_type(2)));
typedef float f32x4 __attribute__((ext_vector_type(4)));
typedef float f32x16 __attribute__((ext_vector_type(16)));
typedef unsigned uint32x4 __attribute__((ext_vector_type(4)));

#define MM 4096   // B*S
#define NN 1024   // E
#define KK 1024   // E

__device__ __forceinline__ void gload_lds16(const void* g, void* l) {
  __builtin_amdgcn_global_load_lds(
      (const __attribute__((address_space(1))) void*)g,
      (__attribute__((address_space(3))) void*)l, 16, 0, 0);
}

// v_cvt_pk_bf16_f32: D.lo16 = bf16(lo), D.hi16 = bf16(hi). No builtin on gfx950.
__device__ __forceinline__ unsigned cvt_pk_bf16(float lo, float hi) {
  unsigned r;
  asm("v_cvt_pk_bf16_f32 %0, %1, %2" : "=v"(r) : "v"(lo), "v"(hi));
  return r;
}

// pack 8 f32 (two float4) -> bf16x8, same (bf16) cast as the old cvt_all path
__device__ __forceinline__ bf16x8 cvt8(float4 a, float4 b) {
  bf16x8 o;
  o[0] = (bf16)a.x; o[1] = (bf16)a.y; o[2] = (bf16)a.z; o[3] = (bf16)a.w;
  o[4] = (bf16)b.x; o[5] = (bf16)b.y; o[6] = (bf16)b.z; o[7] = (bf16)b.w;
  return o;
}

// ---------------- weight converts/transposes -> bf16 ----------------
__global__ __launch_bounds__(256) void cvt_all(const float* __restrict__ Wq,
                                               const float* __restrict__ Wk,
                                               const float* __restrict__ Wv,
                                               const float* __restrict__ Wo,
                                               bf16* __restrict__ Wt,
                                               bf16* __restrict__ Wot)
{
  __shared__ bf16 Sl[64 * 72];
  const int wb = blockIdx.x;           // 0..1023
  const int t = threadIdx.x;
  const int p = wb >> 8, t8 = wb & 255;
  const int ti = t >> 4, c4 = (t & 15) * 4;

  if (p < 3) {
    const float* W = (p == 0) ? Wq : (p == 1 ? Wk : Wv);
    const int h = t8 >> 4, e0 = (t8 & 15) << 6;
#pragma unroll
    for (int r = 0; r < 4; ++r) {
      int e_l = r * 16 + ti;
      float4 val = *(const float4*)(W + (h << 16) + (e0 + e_l) * 64 + c4);
      bf16x4 o; o.x = (bf16)val.x; o.y = (bf16)val.y; o.z = (bf16)val.z; o.w = (bf16)val.w;
      *(bf16x4*)(Sl + e_l * 72 + c4) = o;
    }
    __syncthreads();
#pragma unroll
    for (int r = 0; r < 4; ++r) {
      int d_l = r * 16 + ti;
      bf16x4 o;
      o.x = Sl[(c4 + 0) * 72 + d_l];
      o.y = Sl[(c4 + 1) * 72 + d_l];
      o.z = Sl[(c4 + 2) * 72 + d_l];
      o.w = Sl[(c4 + 3) * 72 + d_l];
      *(bf16x4*)(Wt + (size_t)p * 1048576 + (size_t)((h << 6) + d_l) * 1024 + e0 + c4) = o;
    }
  } else {
    const int n0 = (t8 >> 4) << 6, k0 = (t8 & 15) << 6;
#pragma unroll
    for (int r = 0; r < 4; ++r) {
      int k_l = r * 16 + ti;
      float4 val = *(const float4*)(Wo + (size_t)(k0 + k_l) * 1024 + n0 + c4);
      bf16x4 o; o.x = (bf16)val.x; o.y = (bf16)val.y; o.z = (bf16)val.z; o.w = (bf16)val.w;
      *(bf16x4*)(Sl + k_l * 72 + c4) = o;
    }
    __syncthreads();
#pragma unroll
    for (int r = 0; r < 4; ++r) {
      int n_l = r * 16 + ti;
      bf16x4 o;
      o.x = Sl[(c4 + 0) * 72 + n_l];
      o.y = Sl[(c4 + 1) * 72 + n_l];
      o.z = Sl[(c4 + 2) * 72 + n_l];
      o.w = Sl[(c4 + 3) * 72 + n_l];
      *(bf16x4*)(Wot + (size_t)(n0 + n_l) * 1024 + k0 + c4) = o;
    }
  }
}

// ---------------- projection GEMM: f32 A read + in-flight cvt (no Xb) ----------
// R11 fix vs R10: the A-prefetch global loads are issued AFTER the staging
// barrier (top of the MFMA phase), not before it. R10 issued them right before
// __syncthreads, whose mandatory s_waitcnt vmcnt(0) (needed for the B
// global_load_lds) drained the just-issued prefetch -> full HBM latency exposed
// per iteration (gemm_proj 64us, MfmaUtil 15%). Now the barrier drain covers
// only B staging; A loads overlap the MFMA phase. Same loads, same values.
__global__ __launch_bounds__(256) void gemm_proj(const float* __restrict__ q,
                                                 const float* __restrict__ k,
                                                 const float* __restrict__ v,
                                                 const bf16* __restrict__ Wt,
                                                 const float* __restrict__ b0,
                                                 const float* __restrict__ b1,
                                                 const float* __restrict__ b2,
                                                 bf16* __restrict__ Out)
{
  __shared__ bf16 As[4096], Bs[4096];
  const int p = blockIdx.y;
  const float* A = (p == 0) ? q : (p == 1 ? k : v);
  const bf16* Bt = Wt + (size_t)p * 1048576;
  const float* bias = (p == 0) ? b0 : (p == 1 ? b1 : b2);
  bf16* C = Out + (size_t)p * 4194304;
  const int bx = blockIdx.x;
  const int m0 = (bx & 31) << 7, n0 = (bx >> 5) << 7;   // m-major XCD remap
  const int tid = threadIdx.x;
  const int w = tid >> 6, L = tid & 63;
  const int quad = L >> 4, l16 = L & 15;
  const int wm = (w & 1) << 6, wn = (w >> 1) << 6;

  const float* Ag = A + (size_t)(m0 + w * 32 + (L >> 2)) * KK + (L & 3) * 8;
  const bf16*  Bg = Bt + (size_t)(n0 + w * 32 + (L >> 2)) * KK + (L & 3) * 8;
  bf16* Al = As + w * 1024;
  bf16* Bl = Bs + w * 1024;

  f32x4 acc[4][4] = {};

  // prefetch A f32 for kt=0 (rows r and r+16 of this wave's 32-row chunk)
  float4 fa0 = *(const float4*)(Ag);
  float4 fa1 = *(const float4*)(Ag + 4);
  float4 fb0 = *(const float4*)(Ag + 16 * KK);
  float4 fb1 = *(const float4*)(Ag + 16 * KK + 4);

  for (int kt = 0; kt < KK / 32; ++kt) {
    __syncthreads();                       // readers of As/Bs from prev iter done
    // A stage: cvt prefetched f32 -> bf16x8, same As layout as gload_lds16 wrote
    *(bf16x8*)(Al + L * 8)       = cvt8(fa0, fa1);
    *(bf16x8*)(Al + 512 + L * 8) = cvt8(fb0, fb1);
    // B stage: async bf16 weights
    const bf16* bgi = Bg + kt * 32;
    gload_lds16(bgi, Bl);
    gload_lds16(bgi + 16 * KK, Bl + 512);
    __syncthreads();                       // drains only B staging (+ ds_writes)
    if (kt + 1 < KK / 32) {                // prefetch next A DURING the MFMA phase
      const float* an = Ag + (kt + 1) * 32;
      fa0 = *(const float4*)(an);
      fa1 = *(const float4*)(an + 4);
      fb0 = *(const float4*)(an + 16 * KK);
      fb1 = *(const float4*)(an + 16 * KK + 4);
    }
    bf16x8 af[4], bfr[4];
#pragma unroll
    for (int mi = 0; mi < 4; ++mi)
      af[mi] = *(const bf16x8*)(As + (wm + mi * 16 + l16) * 32 + quad * 8);
#pragma unroll
    for (int ni = 0; ni < 4; ++ni)
      bfr[ni] = *(const bf16x8*)(Bs + (wn + ni * 16 + l16) * 32 + quad * 8);
#pragma unroll
    for (int mi = 0; mi < 4; ++mi)
#pragma unroll
      for (int ni = 0; ni < 4; ++ni)
        acc[mi][ni] = __builtin_amdgcn_mfma_f32_16x16x32_bf16(af[mi], bfr[ni],
                                                              acc[mi][ni], 0, 0, 0);
  }

#pragma unroll
  for (int ni = 0; ni < 4; ++ni) {
    int col = n0 + wn + ni * 16 + l16;
    float bv = bias[col];
#pragma unroll
    for (int mi = 0; mi < 4; ++mi)
#pragma unroll
      for (int r = 0; r < 4; ++r) {
        int row = m0 + wm + mi * 16 + quad * 4 + r;
        C[(size_t)row * NN + col] = (bf16)(acc[mi][ni][r] + bv);
      }
  }
}

// ---------------- 64x128-tile GEMM for the output projection ----------------
__global__ __launch_bounds__(256) void gemm_outp(const bf16* __restrict__ A,
                                                 const bf16* __restrict__ Bt,
                                                 const float* __restrict__ bias,
                                                 float* __restrict__ C)
{
  __shared__ bf16 As[2048], Bs[4096];
  const int bx = blockIdx.x;
  const int m0 = (bx & 63) << 6, n0 = (bx >> 6) << 7;   // m-major XCD remap
  const int tid = threadIdx.x;
  const int w = tid >> 6, L = tid & 63;
  const int quad = L >> 4, l16 = L & 15;
  const int wm = (w & 1) << 5, wn = (w >> 1) << 6;

  const bf16* Ag = A + (size_t)(m0 + w * 16 + (L >> 2)) * KK + (L & 3) * 8;
  const bf16* Bg = Bt + (size_t)(n0 + w * 32 + (L >> 2)) * KK + (L & 3) * 8;
  bf16* Al = As + w * 512;
  bf16* Bl = Bs + w * 1024;

  f32x4 acc[2][4] = {};
  for (int kt = 0; kt < KK / 32; ++kt) {
    __syncthreads();
    const bf16* a0 = Ag + kt * 32;
    const bf16* b0 = Bg + kt * 32;
    gload_lds16(a0, Al);
    gload_lds16(b0, Bl);
    gload_lds16(b0 + 16 * KK, Bl + 512);
    __syncthreads();
    bf16x8 af[2], bfr[4];
#pragma unroll
    for (int mi = 0; mi < 2; ++mi)
      af[mi] = *(const bf16x8*)(As + (wm + mi * 16 + l16) * 32 + quad * 8);
#pragma unroll
    for (int ni = 0; ni < 4; ++ni)
      bfr[ni] = *(const bf16x8*)(Bs + (wn + ni * 16 + l16) * 32 + quad * 8);
#pragma unroll
    for (int mi = 0; mi < 2; ++mi)
#pragma unroll
      for (int ni = 0; ni < 4; ++ni)
        acc[mi][ni] = __builtin_amdgcn_mfma_f32_16x16x32_bf16(af[mi], bfr[ni],
                                                              acc[mi][ni], 0, 0, 0);
  }

#pragma unroll
  for (int ni = 0; ni < 4; ++ni) {
    int col = n0 + wn + ni * 16 + l16;
    float bv = bias[col];
#pragma unroll
    for (int mi = 0; mi < 2; ++mi)
#pragma unroll
      for (int r = 0; r < 4; ++r) {
        int row = m0 + wm + mi * 16 + quad * 4 + r;
        C[(size_t)row * NN + col] = acc[mi][ni][r] + bv;
      }
  }
}

// ---------------- flash attention v14 (R8 text, passing @ ~50us) -- FROZEN ------
__global__ __launch_bounds__(512) void flash_attn(const bf16* __restrict__ Qm,
                                                  const bf16* __restrict__ Km,
                                                  const bf16* __restrict__ Vm,
                                                  bf16* __restrict__ Om)
{
  __shared__ bf16 Kl[64 * 64];      // 8 KB, [stored key][dh], XOR-swizzled
  __shared__ bf16 Vt[64 * 64];      // 8 KB, [dh][orig key], XOR-swizzled

  const int tid = threadIdx.x;
  const int w = tid >> 6, L = tid & 63;     // w 0..7
  const int l32 = L & 31, hi = L >> 5;
  const int bh = blockIdx.x & 31;
  const int qb = blockIdx.x >> 5;           // 0..7
  const int b = bh >> 4, h = bh & 15;
  const int s0 = qb << 8;                   // 256 q-rows per block
  const size_t base = (size_t)b * 2097152 + h * 64;

  // Q fragments: lane holds Q[q=l32][dh = s*16 + hi*8 + j], scale*log2e folded in.
  bf16x8 qf[4];
  const float SL = 0.03125f * 1.44269504088896f;
  {
    const bf16* qp = Qm + base + (size_t)(s0 + w * 32 + l32) * 1024 + hi * 8;
#pragma unroll
    for (int s = 0; s < 4; ++s) {
      bf16x8 tq = *(const bf16x8*)(qp + s * 16);
#pragma unroll
      for (int j = 0; j < 8; ++j) tq[j] = (bf16)((float)tq[j] * SL);
      qf[s] = tq;
    }
  }

  bf16x8 onesf;
#pragma unroll
  for (int j = 0; j < 8; ++j) onesf[j] = (bf16)1.0f;

  f32x16 oacc0 = {}, oacc1 = {}, lacc = {};

  // K staging: lane L -> Kl row L (orig key 2*l32+hi), wave w -> dh chunk [w*8,+8)
  const bf16* Kg = Km + base + (size_t)(2 * l32 + hi) * 1024 + w * 8;
  // V staging: lane loads orig keys 2*l32, 2*l32+1 at dh slice [dh4, dh4+4)
  const int dh4 = w * 8 + hi * 4;
  const bf16* Vg = Vm + base + (size_t)(2 * l32) * 1024 + dh4;
  const int r7 = l32 & 7;                   // row&7 for rows indexed by l32

  bf16x8 k0 = *(const bf16x8*)Kg;
  bf16x4 va = *(const bf16x4*)Vg;
  bf16x4 vb = *(const bf16x4*)(Vg + 1024);

  for (int kt = 0; kt < 32; ++kt) {
    __syncthreads();  // all waves done reading Kl/Vt from prev iter
    // K: row L, data chunk w at phys chunk w^(L&7)
    *(bf16x8*)(Kl + L * 64 + (((w ^ (L & 7)) << 3))) = k0;
    // V transpose: rows dh4..dh4+3, col pair 2*l32 (b32, same formula as v7)
#pragma unroll
    for (int j = 0; j < 4; ++j) {
      int row = dh4 + j;
      bf16x2 pr; pr.x = va[j]; pr.y = vb[j];
      *(bf16x2*)(Vt + row * 64 + (((l32 >> 2) ^ (row & 7)) << 3) + ((l32 & 3) << 1)) = pr;
    }
    if (kt + 1 < 32) {  // register prefetch (in flight during compute)
      k0 = *(const bf16x8*)(Kg + (size_t)(kt + 1) * 65536);
      va = *(const bf16x4*)(Vg + (size_t)(kt + 1) * 65536);
      vb = *(const bf16x4*)(Vg + (size_t)(kt + 1) * 65536 + 1024);
    }
    __syncthreads();  // staged K/V visible

    // S^T = K Q^T: swapped operands. sa rows = even orig keys 2*m, sb = odd 2*m+1,
    // m = (reg&3)+8*(reg>>2)+4*hi; cols = q = l32 (lane-local q column).
    f32x16 sa = {}, sb = {};
#pragma unroll
    for (int s = 0; s < 4; ++s) {
      bf16x8 kfa = *(const bf16x8*)(Kl + (l32)      * 64 + (((2 * s + hi) ^ r7) << 3));
      bf16x8 kfb = *(const bf16x8*)(Kl + (32 + l32) * 64 + (((2 * s + hi) ^ r7) << 3));
      sa = __builtin_amdgcn_mfma_f32_32x32x16_bf16(kfa, qf[s], sa, 0, 0, 0);
      sb = __builtin_amdgcn_mfma_f32_32x32x16_bf16(kfb, qf[s], sb, 0, 0, 0);
    }

    // exp2 + pack P in-register: paf[s] word t = keys (16s+8hi+2t, +1). Lane-local.
    bf16x8 paf[4];
#pragma unroll
    for (int s = 0; s < 4; ++s) {
      uint32x4 wv;
#pragma unroll
      for (int t = 0; t < 4; ++t) {
        float pe = __builtin_amdgcn_exp2f(sa[4 * s + t]);
        float po = __builtin_amdgcn_exp2f(sb[4 * s + t]);
        wv[t] = cvt_pk_bf16(pe, po);
      }
      paf[s] = __builtin_bit_cast(bf16x8, wv);
    }

    // O += P V^T; l += P ones  (same bf16 paf as PV -> O/l rounding cancellation)
#pragma unroll
    for (int s = 0; s < 4; ++s) {
      bf16x8 vf0 = *(const bf16x8*)(Vt + (l32)      * 64 + (((2 * s + hi) ^ r7) << 3));
      bf16x8 vf1 = *(const bf16x8*)(Vt + (32 + l32) * 64 + (((2 * s + hi) ^ r7) << 3));
      oacc0 = __builtin_amdgcn_mfma_f32_32x32x16_bf16(paf[s], vf0, oacc0, 0, 0, 0);
      oacc1 = __builtin_amdgcn_mfma_f32_32x32x16_bf16(paf[s], vf1, oacc1, 0, 0, 0);
      lacc  = __builtin_amdgcn_mfma_f32_32x32x16_bf16(paf[s], onesf, lacc, 0, 0, 0);
    }
  }

  // ---- epilogue: every lane holds l for its 16 C-rows in lacc (all cols equal) ----
#pragma unroll
  for (int reg = 0; reg < 16; ++reg) {
    int row = (reg & 3) + ((reg >> 2) << 3) + (hi << 2);
    float inv = 1.f / lacc[reg];
    bf16* op = Om + base + (size_t)(s0 + w * 32 + row) * 1024;
    op[l32]      = (bf16)(oacc0[reg] * inv);
    op[32 + l32] = (bf16)(oacc1[reg] * inv);
  }
}

extern "C" void kernel_launch(void* const* d_in, const int* in_sizes, int n_in,
                              void* d_out, int out_size, void* d_ws, size_t ws_size,
                              hipStream_t stream)
{
  const float* q  = (const float*)d_in[0];
  const float* k  = (const float*)d_in[1];
  const float* v  = (const float*)d_in[2];
  const float* Wq = (const float*)d_in[3];
  const float* bq = (const float*)d_in[4];
  const float* Wk = (const float*)d_in[5];
  const float* bk = (const float*)d_in[6];
  const float* Wv = (const float*)d_in[7];
  const float* bv = (const float*)d_in[8];
  const float* Wo = (const float*)d_in[9];
  const float* bo = (const float*)d_in[10];

  char* ws = (char*)d_ws;
  bf16* Wt  = (bf16*)(ws + 25165824);       // 3 x 1024x1024 bf16
  bf16* Wot = (bf16*)(ws + 31457280);       // 1024x1024 bf16
  bf16* QKV = (bf16*)(ws + 33554432);       // 3 x 4096x1024 bf16
  bf16* O   = (bf16*)ws;                    // flash output (ws[0..8MB], free)

  cvt_all<<<dim3(1024), 256, 0, stream>>>(Wq, Wk, Wv, Wo, Wt, Wot);
  gemm_proj<<<dim3(256, 3), 256, 0, stream>>>(q, k, v, Wt, bq, bk, bv, QKV);
  flash_attn<<<dim3(256), 512, 0, stream>>>(QKV, QKV + 4194304, QKV + 8388608, O);
  gemm_outp<<<dim3(512), 256, 0, stream>>>(O, Wot, bo, (float*)d_out);
}

// Round 13
// 218.411 us; speedup vs baseline: 1.0373x; 1.0373x over previous
//
#include <hip/hip_runtime.h>

typedef __bf16 bf16;
typedef __bf16 bf16x8 __attribute__((ext_vector_type(8)));
typedef __bf16 bf16x4 __attribute__((ext_vector_type(4)));
typedef __bf16 bf16x2 __attribute__((ext_vector_type(2)));
typedef float f32x4 __attribute__((ext_vector_type(4)));
typedef float f32x16 __attribute__((ext_vector_type(16)));
typedef unsigned uint32x4 __attribute__((ext_vector_type(4)));

#define MM 4096   // B*S
#define NN 1024   // E
#define KK 1024   // E

__device__ __forceinline__ void gload_lds16(const void* g, void* l) {
  __builtin_amdgcn_global_load_lds(
      (const __attribute__((address_space(1))) void*)g,
      (__attribute__((address_space(3))) void*)l, 16, 0, 0);
}

// v_cvt_pk_bf16_f32: D.lo16 = bf16(lo), D.hi16 = bf16(hi). No builtin on gfx950.
__device__ __forceinline__ unsigned cvt_pk_bf16(float lo, float hi) {
  unsigned r;
  asm("v_cvt_pk_bf16_f32 %0, %1, %2" : "=v"(r) : "v"(lo), "v"(hi));
  return r;
}

// ---------------- fused converts: activations + weights -> bf16 ----------------
// Activation pass: 4 float4s per thread (grid 4096 blocks, ILP). Weight part
// transposes via LDS. This is the R7-verified text (absmax 4.88e-4, reproduced).
__global__ __launch_bounds__(256) void cvt_all(const float* __restrict__ q,
                                               const float* __restrict__ k,
                                               const float* __restrict__ v,
                                               const float* __restrict__ Wq,
                                               const float* __restrict__ Wk,
                                               const float* __restrict__ Wv,
                                               const float* __restrict__ Wo,
                                               bf16* __restrict__ Xb,
                                               bf16* __restrict__ Wt,
                                               bf16* __restrict__ Wot)
{
  __shared__ bf16 Sl[64 * 72];
  const int bid = blockIdx.x;
  const int t = threadIdx.x;

  if (bid < 3072) {
    int p = bid >> 10, bx = bid & 1023;        // 1024 blocks x 4096 floats per tensor
    const float* src = (p == 0) ? q : (p == 1 ? k : v);
    bf16* dst = Xb + (size_t)p * (MM * (size_t)KK);
#pragma unroll
    for (int r = 0; r < 4; ++r) {
      int i = bx * 4096 + r * 1024 + t * 4;
      float4 val = *(const float4*)(src + i);
      bf16x4 o;
      o.x = (bf16)val.x; o.y = (bf16)val.y; o.z = (bf16)val.z; o.w = (bf16)val.w;
      *(bf16x4*)(dst + i) = o;
    }
    return;
  }

  const int wb = bid - 3072;           // 0..1023
  const int p = wb >> 8, t8 = wb & 255;
  const int ti = t >> 4, c4 = (t & 15) * 4;

  if (p < 3) {
    const float* W = (p == 0) ? Wq : (p == 1 ? Wk : Wv);
    const int h = t8 >> 4, e0 = (t8 & 15) << 6;
#pragma unroll
    for (int r = 0; r < 4; ++r) {
      int e_l = r * 16 + ti;
      float4 val = *(const float4*)(W + (h << 16) + (e0 + e_l) * 64 + c4);
      bf16x4 o; o.x = (bf16)val.x; o.y = (bf16)val.y; o.z = (bf16)val.z; o.w = (bf16)val.w;
      *(bf16x4*)(Sl + e_l * 72 + c4) = o;
    }
    __syncthreads();
#pragma unroll
    for (int r = 0; r < 4; ++r) {
      int d_l = r * 16 + ti;
      bf16x4 o;
      o.x = Sl[(c4 + 0) * 72 + d_l];
      o.y = Sl[(c4 + 1) * 72 + d_l];
      o.z = Sl[(c4 + 2) * 72 + d_l];
      o.w = Sl[(c4 + 3) * 72 + d_l];
      *(bf16x4*)(Wt + (size_t)p * 1048576 + (size_t)((h << 6) + d_l) * 1024 + e0 + c4) = o;
    }
  } else {
    const int n0 = (t8 >> 4) << 6, k0 = (t8 & 15) << 6;
#pragma unroll
    for (int r = 0; r < 4; ++r) {
      int k_l = r * 16 + ti;
      float4 val = *(const float4*)(Wo + (size_t)(k0 + k_l) * 1024 + n0 + c4);
      bf16x4 o; o.x = (bf16)val.x; o.y = (bf16)val.y; o.z = (bf16)val.z; o.w = (bf16)val.w;
      *(bf16x4*)(Sl + k_l * 72 + c4) = o;
    }
    __syncthreads();
#pragma unroll
    for (int r = 0; r < 4; ++r) {
      int n_l = r * 16 + ti;
      bf16x4 o;
      o.x = Sl[(c4 + 0) * 72 + n_l];
      o.y = Sl[(c4 + 1) * 72 + n_l];
      o.z = Sl[(c4 + 2) * 72 + n_l];
      o.w = Sl[(c4 + 3) * 72 + n_l];
      *(bf16x4*)(Wot + (size_t)(n0 + n_l) * 1024 + k0 + c4) = o;
    }
  }
}

// ---------------- m97-style 128x128 bf16 GEMM core ----------------
__device__ __forceinline__ void gemm_body(const bf16* __restrict__ A,
                                          const bf16* __restrict__ Bt,
                                          bf16* As, bf16* Bs,
                                          int m0, int n0, f32x4 (&acc)[4][4])
{
  const int tid = threadIdx.x;
  const int w = tid >> 6, L = tid & 63;
  const int quad = L >> 4, l16 = L & 15;
  const int wm = (w & 1) << 6, wn = (w >> 1) << 6;

  const bf16* Ag = A + (size_t)(m0 + w * 32 + (L >> 2)) * KK + (L & 3) * 8;
  const bf16* Bg = Bt + (size_t)(n0 + w * 32 + (L >> 2)) * KK + (L & 3) * 8;
  bf16* Al = As + w * 1024;
  bf16* Bl = Bs + w * 1024;

  for (int kt = 0; kt < KK / 32; ++kt) {
    __syncthreads();
    const bf16* a0 = Ag + kt * 32;
    const bf16* b0 = Bg + kt * 32;
    gload_lds16(a0, Al);
    gload_lds16(a0 + 16 * KK, Al + 512);
    gload_lds16(b0, Bl);
    gload_lds16(b0 + 16 * KK, Bl + 512);
    __syncthreads();
    bf16x8 af[4], bfr[4];
#pragma unroll
    for (int mi = 0; mi < 4; ++mi)
      af[mi] = *(const bf16x8*)(As + (wm + mi * 16 + l16) * 32 + quad * 8);
#pragma unroll
    for (int ni = 0; ni < 4; ++ni)
      bfr[ni] = *(const bf16x8*)(Bs + (wn + ni * 16 + l16) * 32 + quad * 8);
#pragma unroll
    for (int mi = 0; mi < 4; ++mi)
#pragma unroll
      for (int ni = 0; ni < 4; ++ni)
        acc[mi][ni] = __builtin_amdgcn_mfma_f32_16x16x32_bf16(af[mi], bfr[ni],
                                                              acc[mi][ni], 0, 0, 0);
  }
}

__global__ __launch_bounds__(256) void gemm_proj(const bf16* __restrict__ X,
                                                 const bf16* __restrict__ Wt,
                                                 const float* __restrict__ b0,
                                                 const float* __restrict__ b1,
                                                 const float* __restrict__ b2,
                                                 bf16* __restrict__ Out)
{
  __shared__ bf16 As[4096], Bs[4096];
  int p = blockIdx.y;
  const bf16* A = X + (size_t)p * 4194304;
  const bf16* Bt = Wt + (size_t)p * 1048576;
  const float* bias = (p == 0) ? b0 : (p == 1 ? b1 : b2);
  bf16* C = Out + (size_t)p * 4194304;
  int bx = blockIdx.x;
  int m0 = (bx >> 3) << 7, n0 = (bx & 7) << 7;
  f32x4 acc[4][4] = {};
  gemm_body(A, Bt, As, Bs, m0, n0, acc);
  const int L = threadIdx.x & 63, w = threadIdx.x >> 6;
  const int quad = L >> 4, l16 = L & 15;
  const int wm = (w & 1) << 6, wn = (w >> 1) << 6;
#pragma unroll
  for (int ni = 0; ni < 4; ++ni) {
    int col = n0 + wn + ni * 16 + l16;
    float bv = bias[col];
#pragma unroll
    for (int mi = 0; mi < 4; ++mi)
#pragma unroll
      for (int r = 0; r < 4; ++r) {
        int row = m0 + wm + mi * 16 + quad * 4 + r;
        C[(size_t)row * NN + col] = (bf16)(acc[mi][ni][r] + bv);
      }
  }
}

// ---------------- 64x128-tile GEMM for the output projection ----------------
__global__ __launch_bounds__(256) void gemm_outp(const bf16* __restrict__ A,
                                                 const bf16* __restrict__ Bt,
                                                 const float* __restrict__ bias,
                                                 float* __restrict__ C)
{
  __shared__ bf16 As[2048], Bs[4096];
  const int bx = blockIdx.x;
  const int m0 = (bx >> 3) << 6, n0 = (bx & 7) << 7;
  const int tid = threadIdx.x;
  const int w = tid >> 6, L = tid & 63;
  const int quad = L >> 4, l16 = L & 15;
  const int wm = (w & 1) << 5, wn = (w >> 1) << 6;

  const bf16* Ag = A + (size_t)(m0 + w * 16 + (L >> 2)) * KK + (L & 3) * 8;
  const bf16* Bg = Bt + (size_t)(n0 + w * 32 + (L >> 2)) * KK + (L & 3) * 8;
  bf16* Al = As + w * 512;
  bf16* Bl = Bs + w * 1024;

  f32x4 acc[2][4] = {};
  for (int kt = 0; kt < KK / 32; ++kt) {
    __syncthreads();
    const bf16* a0 = Ag + kt * 32;
    const bf16* b0 = Bg + kt * 32;
    gload_lds16(a0, Al);
    gload_lds16(b0, Bl);
    gload_lds16(b0 + 16 * KK, Bl + 512);
    __syncthreads();
    bf16x8 af[2], bfr[4];
#pragma unroll
    for (int mi = 0; mi < 2; ++mi)
      af[mi] = *(const bf16x8*)(As + (wm + mi * 16 + l16) * 32 + quad * 8);
#pragma unroll
    for (int ni = 0; ni < 4; ++ni)
      bfr[ni] = *(const bf16x8*)(Bs + (wn + ni * 16 + l16) * 32 + quad * 8);
#pragma unroll
    for (int mi = 0; mi < 2; ++mi)
#pragma unroll
      for (int ni = 0; ni < 4; ++ni)
        acc[mi][ni] = __builtin_amdgcn_mfma_f32_16x16x32_bf16(af[mi], bfr[ni],
                                                              acc[mi][ni], 0, 0, 0);
  }

#pragma unroll
  for (int ni = 0; ni < 4; ++ni) {
    int col = n0 + wn + ni * 16 + l16;
    float bv = bias[col];
#pragma unroll
    for (int mi = 0; mi < 2; ++mi)
#pragma unroll
      for (int r = 0; r < 4; ++r) {
        int row = m0 + wm + mi * 16 + quad * 4 + r;
        C[(size_t)row * NN + col] = acc[mi][ni][r] + bv;
      }
  }
}

// ---------------- flash attention v7 (EXACT R1/R7 text, reproduced passing) ------
// absmax 4.882812e-4, bit-reproduced across two containers (R1, R7). All
// structural mutations (v8-v14: presum-lacc, 128-key rounds+setprio, key-split,
// double-buffer, 8-wave shared K/V) failed numerics, regressed, or showed
// run-to-run absmax instability at the pass threshold. DO NOT MODIFY.
__global__ __launch_bounds__(256) void flash_attn(const bf16* __restrict__ Qm,
                                                  const bf16* __restrict__ Km,
                                                  const bf16* __restrict__ Vm,
                                                  bf16* __restrict__ Om)
{
  __shared__ bf16 Kl[64 * 64];      // 8 KB, [stored key][dh], XOR-swizzled
  __shared__ bf16 Vt[64 * 64];      // 8 KB, [dh][orig key], XOR-swizzled

  const int tid = threadIdx.x;
  const int w = tid >> 6, L = tid & 63;
  const int l32 = L & 31, hi = L >> 5;
  const int bh = blockIdx.x & 31;
  const int qb = blockIdx.x >> 5;
  const int b = bh >> 4, h = bh & 15;
  const int s0 = qb << 7;                       // 128 q-rows per block
  const size_t base = (size_t)b * 2097152 + h * 64;

  // Q fragments: lane holds Q[q=l32][dh = s*16 + hi*8 + j], scale*log2e folded in.
  // Same data serves as the B-operand of the swapped QK^T (B[k=dh][n=q]).
  bf16x8 qf[4];
  const float SL = 0.03125f * 1.44269504088896f;
  {
    const bf16* qp = Qm + base + (size_t)(s0 + w * 32 + l32) * 1024 + hi * 8;
#pragma unroll
    for (int s = 0; s < 4; ++s) {
      bf16x8 tq = *(const bf16x8*)(qp + s * 16);
#pragma unroll
      for (int j = 0; j < 8; ++j) tq[j] = (bf16)((float)tq[j] * SL);
      qf[s] = tq;
    }
  }

  bf16x8 onesf;
#pragma unroll
  for (int j = 0; j < 8; ++j) onesf[j] = (bf16)1.0f;

  f32x16 oacc0 = {}, oacc1 = {}, lacc = {};

  // K staging: lane L fills Kl row L <- orig key 2*l32+hi, dh chunk [w*16, w*16+16)
  const bf16* Kg = Km + base + (size_t)(2 * l32 + hi) * 1024 + w * 16;
  // V staging: lane L loads orig keys 2*l32, 2*l32+1 at dh slice dh8 = w*16+hi*8
  const int dh8 = w * 16 + hi * 8;
  const bf16* Vg = Vm + base + (size_t)(2 * l32) * 1024 + dh8;
  const int r7 = l32 & 7;                       // row&7 for rows indexed by l32

  bf16x8 k0 = *(const bf16x8*)Kg;
  bf16x8 k1 = *(const bf16x8*)(Kg + 8);
  bf16x8 va = *(const bf16x8*)Vg;
  bf16x8 vb = *(const bf16x8*)(Vg + 1024);

  for (int kt = 0; kt < 32; ++kt) {
    __syncthreads();  // all waves done reading Kl/Vt from prev iter
    // K: row L, chunks 2w, 2w+1 (XOR row&7)
    *(bf16x8*)(Kl + L * 64 + ((((2 * w + 0) ^ (L & 7)) << 3))) = k0;
    *(bf16x8*)(Kl + L * 64 + ((((2 * w + 1) ^ (L & 7)) << 3))) = k1;
    // V transpose: row dh8+j, col pair 2*l32 (b32, conflict-free)
#pragma unroll
    for (int j = 0; j < 8; ++j) {
      int row = dh8 + j;
      bf16x2 pr; pr.x = va[j]; pr.y = vb[j];
      *(bf16x2*)(Vt + row * 64 + (((l32 >> 2) ^ (row & 7)) << 3) + ((l32 & 3) << 1)) = pr;
    }
    if (kt + 1 < 32) {  // register prefetch (in flight during compute)
      k0 = *(const bf16x8*)(Kg + (size_t)(kt + 1) * 65536);
      k1 = *(const bf16x8*)(Kg + (size_t)(kt + 1) * 65536 + 8);
      va = *(const bf16x8*)(Vg + (size_t)(kt + 1) * 65536);
      vb = *(const bf16x8*)(Vg + (size_t)(kt + 1) * 65536 + 1024);
    }
    __syncthreads();  // staged K/V visible

    // S^T = K Q^T: swapped operands. sa rows = even orig keys 2*m, sb = odd 2*m+1,
    // m = (reg&3)+8*(reg>>2)+4*hi; cols = q = l32 (lane-local q column).
    f32x16 sa = {}, sb = {};
#pragma unroll
    for (int s = 0; s < 4; ++s) {
      bf16x8 kfa = *(const bf16x8*)(Kl + (l32)      * 64 + (((2 * s + hi) ^ r7) << 3));
      bf16x8 kfb = *(const bf16x8*)(Kl + (32 + l32) * 64 + (((2 * s + hi) ^ r7) << 3));
      sa = __builtin_amdgcn_mfma_f32_32x32x16_bf16(kfa, qf[s], sa, 0, 0, 0);
      sb = __builtin_amdgcn_mfma_f32_32x32x16_bf16(kfb, qf[s], sb, 0, 0, 0);
    }

    // exp2 + pack P in-register: paf[s] word w = keys (16s+8hi+2w, 16s+8hi+2w+1)
    //   = (even key 2m, odd key 2m+1) with m = 8s+4hi+w = reg 4s+w of sa/sb. Local!
    bf16x8 paf[4];
#pragma unroll
    for (int s = 0; s < 4; ++s) {
      uint32x4 wv;
#pragma unroll
      for (int t = 0; t < 4; ++t) {
        float pe = __builtin_amdgcn_exp2f(sa[4 * s + t]);
        float po = __builtin_amdgcn_exp2f(sb[4 * s + t]);
        wv[t] = cvt_pk_bf16(pe, po);
      }
      paf[s] = __builtin_bit_cast(bf16x8, wv);
    }

    // O += P V^T; l += P ones  (paf layout identical to v6: A[m=q=l32][k=orig key])
#pragma unroll
    for (int s = 0; s < 4; ++s) {
      bf16x8 vf0 = *(const bf16x8*)(Vt + (l32)      * 64 + (((2 * s + hi) ^ r7) << 3));
      bf16x8 vf1 = *(const bf16x8*)(Vt + (32 + l32) * 64 + (((2 * s + hi) ^ r7) << 3));
      oacc0 = __builtin_amdgcn_mfma_f32_32x32x16_bf16(paf[s], vf0, oacc0, 0, 0, 0);
      oacc1 = __builtin_amdgcn_mfma_f32_32x32x16_bf16(paf[s], vf1, oacc1, 0, 0, 0);
      lacc  = __builtin_amdgcn_mfma_f32_32x32x16_bf16(paf[s], onesf, lacc, 0, 0, 0);
    }
  }

  // ---- epilogue: every lane holds l for its 16 C-rows in lacc (all cols equal) ----
#pragma unroll
  for (int reg = 0; reg < 16; ++reg) {
    int row = (reg & 3) + ((reg >> 2) << 3) + (hi << 2);
    float inv = 1.f / lacc[reg];
    bf16* op = Om + base + (size_t)(s0 + w * 32 + row) * 1024;
    op[l32]      = (bf16)(oacc0[reg] * inv);
    op[32 + l32] = (bf16)(oacc1[reg] * inv);
  }
}

extern "C" void kernel_launch(void* const* d_in, const int* in_sizes, int n_in,
                              void* d_out, int out_size, void* d_ws, size_t ws_size,
                              hipStream_t stream)
{
  const float* q  = (const float*)d_in[0];
  const float* k  = (const float*)d_in[1];
  const float* v  = (const float*)d_in[2];
  const float* Wq = (const float*)d_in[3];
  const float* bq = (const float*)d_in[4];
  const float* Wk = (const float*)d_in[5];
  const float* bk = (const float*)d_in[6];
  const float* Wv = (const float*)d_in[7];
  const float* bv = (const float*)d_in[8];
  const float* Wo = (const float*)d_in[9];
  const float* bo = (const float*)d_in[10];

  char* ws = (char*)d_ws;
  bf16* Xb  = (bf16*)ws;                    // 3 x 4096x1024 bf16 (dead after gemm_proj)
  bf16* Wt  = (bf16*)(ws + 25165824);       // 3 x 1024x1024 bf16
  bf16* Wot = (bf16*)(ws + 31457280);       // 1024x1024 bf16
  bf16* QKV = (bf16*)(ws + 33554432);       // 3 x 4096x1024 bf16
  bf16* O   = (bf16*)ws;                    // aliases Xb

  cvt_all<<<dim3(4096), 256, 0, stream>>>(q, k, v, Wq, Wk, Wv, Wo, Xb, Wt, Wot);
  gemm_proj<<<dim3(256, 3), 256, 0, stream>>>(Xb, Wt, bq, bk, bv, QKV);
  flash_attn<<<dim3(512), 256, 0, stream>>>(QKV, QKV + 4194304, QKV + 8388608, O);
  gemm_outp<<<dim3(512), 256, 0, stream>>>(O, Wot, bo, (float*)d_out);
}